// Round 11
// baseline (136.527 us; speedup 1.0000x reference)
//
#include <hip/hip_runtime.h>
#include <cstdint>
#include <cstddef>

// ---------------------------------------------------------------------------
// RetentionLayer: x->(QKVG proj + RoPE/SiLU) -> causal decay retention ->
// GroupNorm(64)*gate -> @ Wo^T.   B=2 S=2048 D=1024 H=16 Dh=64. Output f32.
// Retention via CHUNKED RECURRENCE (chunk=64).
// Projection GEMM: 256x256 tile, BK=64, 8 waves, 128KB LDS double-buffer,
// 4-phase compute per K-tile, COUNTED vmcnt(8) prefetch (never 0 in loop).
// Final GEMM: 128x64 tile r8-proven 2-phase structure, 512 blocks.
// ---------------------------------------------------------------------------

typedef __attribute__((ext_vector_type(4))) float  f32x4;
typedef __attribute__((ext_vector_type(8))) short  bf16x8;
typedef __attribute__((ext_vector_type(4))) short  bf16x4v;
typedef __attribute__((ext_vector_type(2))) unsigned int u32x2;

#define MFMA_BF16 __builtin_amdgcn_mfma_f32_16x16x32_bf16

// global_load_lds width=16: per-lane global src, wave-uniform LDS base
#define GLL16(gp, lp) __builtin_amdgcn_global_load_lds( \
    (const __attribute__((address_space(1))) unsigned int*)(const void*)(gp), \
    (__attribute__((address_space(3))) unsigned int*)(void*)(lp), 16, 0, 0)

#define WAITV(N) asm volatile("s_waitcnt vmcnt(" #N ")" ::: "memory")
#define BARRIER  asm volatile("s_barrier" ::: "memory")

__device__ __forceinline__ unsigned short f2bf(float f) {
    unsigned u = __float_as_uint(f);
    u += 0x7fffu + ((u >> 16) & 1u);   // RNE
    return (unsigned short)(u >> 16);
}
__device__ __forceinline__ float bf2f(unsigned short h) {
    return __uint_as_float(((unsigned)h) << 16);
}
__device__ __forceinline__ unsigned cvt_pk_bf16(float lo, float hi) {
    unsigned r;
    asm("v_cvt_pk_bf16_f32 %0, %1, %2" : "=v"(r) : "v"(lo), "v"(hi));
    return r;
}

// ---------------------------------------------------------------------------
// f32 -> bf16 convert: x (4096x1024) then Wq,Wk,Wv,Wg,Wo (1024x1024 each).
// Blocks < 256 additionally fill the RoPE tables (65536 entries each).
// ---------------------------------------------------------------------------
__global__ void convert_kernel(const float* __restrict__ x,
                               const float* __restrict__ wq, const float* __restrict__ wk,
                               const float* __restrict__ wv, const float* __restrict__ wg,
                               const float* __restrict__ wo,
                               unsigned short* __restrict__ dst,
                               float* __restrict__ cosT, float* __restrict__ sinT) {
    const size_t total = 4194304u + 5u * 1048576u;  // 9437184
    for (size_t i = (size_t)blockIdx.x * blockDim.x + threadIdx.x;
         i * 4 < total; i += (size_t)gridDim.x * blockDim.x) {
        size_t e = i * 4;
        const float* src; size_t off;
        if (e < 4194304u) { src = x; off = e; }
        else {
            size_t r = e - 4194304u;
            int w = (int)(r >> 20); off = r & 1048575u;
            src = (w == 0) ? wq : (w == 1) ? wk : (w == 2) ? wv : (w == 3) ? wg : wo;
        }
        f32x4 v = *(const f32x4*)(src + off);
        unsigned short o0 = f2bf(v[0]), o1 = f2bf(v[1]), o2 = f2bf(v[2]), o3 = f2bf(v[3]);
        unsigned long long pack = (unsigned long long)o0 | ((unsigned long long)o1 << 16)
                                | ((unsigned long long)o2 << 32) | ((unsigned long long)o3 << 48);
        *(unsigned long long*)(dst + e) = pack;
    }
    if (blockIdx.x < 256) {
        int i = blockIdx.x * 256 + threadIdx.x;   // 65536 entries
        int s = i >> 5, j = i & 31;
        float inv = exp2f(-(float)j * (13.287712379549449f / 32.0f)); // log2(10000)
        float ang = (float)s * inv;
        cosT[i] = cosf(ang);
        sinT[i] = sinf(ang);
    }
}

// ---------------------------------------------------------------------------
// Projection GEMM: C[4096,1024] = x @ W^T for modes 0..3 (blockIdx.z).
// 256x256 tile, BK=64, 512 threads = 8 waves (2M x 4N, per-wave 128x64).
// LDS: 2 parities x (A 32KB + B 32KB) = 128KB -> 1 block/CU, 2 waves/SIMD.
// Pipeline: prologue stages tiles 0,1; iter t: vmcnt(8)+barrier (tile t
// landed, t+1 in flight) -> 4 compute phases -> stage t+2 into freed parity.
// mode 0: ->q_hm (+RoPE)   1: ->k_hm (+RoPE) AND kTs   2: ->vT (C^T)
// mode 3: ->gate bf16 (SiLU)
// ---------------------------------------------------------------------------
__launch_bounds__(512, 2)
__global__ void gemm256_proj(const unsigned short* __restrict__ A_x,
                             const unsigned short* __restrict__ Wq, const unsigned short* __restrict__ Wk,
                             const unsigned short* __restrict__ Wv, const unsigned short* __restrict__ Wg,
                             const float* __restrict__ cosT, const float* __restrict__ sinT,
                             unsigned short* __restrict__ q_hm, unsigned short* __restrict__ k_hm,
                             unsigned short* __restrict__ kTs, unsigned short* __restrict__ vT,
                             unsigned short* __restrict__ gate) {
    int mode = blockIdx.z;
    const unsigned short* W = (mode == 0) ? Wq : (mode == 1) ? Wk :
                              (mode == 2) ? Wv : Wg;

    __shared__ __align__(16) unsigned short Ash[2][256 * 64];   // 64 KB
    __shared__ __align__(16) unsigned short Bsh[2][256 * 64];   // 64 KB

    int tid = threadIdx.x;
    int lane = tid & 63, wid = tid >> 6;
    int wr = wid >> 2, wc = wid & 3;            // 2M x 4N waves
    int m0 = blockIdx.y * 256, n0 = blockIdx.x * 256;
    int q_lane = lane & 15;

    // staging: one GLL16 = 512 lanes x 16B = 64 rows x 128B.  Thread (tid>>3,
    // tid&7): row-in-issue, chunk.  Source chunk pre-swizzled ^ (row&7);
    // LDS dest linear (wave-uniform base + lane*16).
    int s_row = tid >> 3;                        // 0..63
    int s_c   = ((tid & 7) ^ (s_row & 7)) << 3;  // source col offset (shorts)
    const unsigned short* Ab = A_x + (size_t)(m0 + s_row) * 1024 + s_c;
    const unsigned short* Wb = W   + (size_t)(n0 + s_row) * 1024 + s_c;

    f32x4 acc[8][4];
#pragma unroll
    for (int i = 0; i < 8; ++i)
#pragma unroll
        for (int j = 0; j < 4; ++j)
#pragma unroll
            for (int r = 0; r < 4; ++r) acc[i][j][r] = 0.0f;

    auto stage = [&](int p, int t) {
        int k0 = t * 64;
#pragma unroll
        for (int i = 0; i < 4; ++i)
            GLL16(Ab + (size_t)(i * 64) * 1024 + k0, &Ash[p][(i * 64 + wid * 8) * 64]);
#pragma unroll
        for (int i = 0; i < 4; ++i)
            GLL16(Wb + (size_t)(i * 64) * 1024 + k0, &Bsh[p][(i * 64 + wid * 8) * 64]);
    };

    // 4 phases per K-tile; phase q computes quadrant (mi-half q>>1, ni-half q&1)
    auto compute = [&](int p) {
#pragma unroll
        for (int q = 0; q < 4; ++q) {
            const int mi0 = (q >> 1) * 4, ni0 = (q & 1) * 2;
            bf16x8 af[4][2], bfv[2][2];
#pragma unroll
            for (int mi = 0; mi < 4; ++mi)
#pragma unroll
                for (int ks = 0; ks < 2; ++ks) {
                    int row = wr * 128 + (mi0 + mi) * 16 + q_lane;
                    int c = ks * 4 + (lane >> 4);
                    af[mi][ks] = *(const bf16x8*)&Ash[p][row * 64 + ((c ^ (row & 7)) << 3)];
                }
#pragma unroll
            for (int ni = 0; ni < 2; ++ni)
#pragma unroll
                for (int ks = 0; ks < 2; ++ks) {
                    int row = wc * 64 + (ni0 + ni) * 16 + q_lane;
                    int c = ks * 4 + (lane >> 4);
                    bfv[ni][ks] = *(const bf16x8*)&Bsh[p][row * 64 + ((c ^ (row & 7)) << 3)];
                }
            BARRIER;                              // align waves pre-MFMA
            __builtin_amdgcn_s_setprio(1);
            if (mode == 2) {   // C^T: swap operands
#pragma unroll
                for (int mi = 0; mi < 4; ++mi)
#pragma unroll
                    for (int ni = 0; ni < 2; ++ni)
#pragma unroll
                        for (int ks = 0; ks < 2; ++ks)
                            acc[mi0 + mi][ni0 + ni] =
                                MFMA_BF16(bfv[ni][ks], af[mi][ks], acc[mi0 + mi][ni0 + ni], 0, 0, 0);
            } else {
#pragma unroll
                for (int mi = 0; mi < 4; ++mi)
#pragma unroll
                    for (int ni = 0; ni < 2; ++ni)
#pragma unroll
                        for (int ks = 0; ks < 2; ++ks)
                            acc[mi0 + mi][ni0 + ni] =
                                MFMA_BF16(af[mi][ks], bfv[ni][ks], acc[mi0 + mi][ni0 + ni], 0, 0, 0);
            }
            __builtin_amdgcn_s_setprio(0);
            BARRIER;                              // phase boundary
        }
    };

    // prologue: stage tiles 0 and 1 (16 loads in flight per wave)
    stage(0, 0);
    stage(1, 1);

    // 16 K-tiles.  Iter t: vmcnt(8) -> tile t landed (t+1's 8 loads stay in
    // flight ACROSS the barrier); compute; stage t+2 into parity t&1 (freed
    // by compute's final barrier: all waves' ds_reads completed before it).
    for (int t = 0; t < 15; ++t) {
        WAITV(8);
        BARRIER;
        compute(t & 1);
        if (t < 14) stage(t & 1, t + 2);
    }
    WAITV(0);                                     // tail: drain tile 15
    BARRIER;
    compute(1);

    // ---- epilogues ----------------------------------------------------
    int mbase = m0 + wr * 128, nbase = n0 + wc * 64;
    int g4 = (lane >> 4) << 2;

    if (mode == 0 || mode == 1) {
        unsigned short* dst = (mode == 0) ? q_hm : k_hm;
        // kTs decay scales (mode 1): h = nbase>>6 is wave-uniform (64-col wave)
        float sr[4] = {1.f, 1.f, 1.f, 1.f}, m16p[4] = {1.f, 1.f, 1.f, 1.f};
        if (mode == 1) {
            float lg = log2f(1.0f - exp2f(-5.0f - (float)(nbase >> 6)));
            float gm1 = exp2f(-lg), gm16 = exp2f(-16.0f * lg);
            sr[0] = exp2f(lg * (float)(63 - g4));       // gamma^{63-g4}
            sr[1] = sr[0] * gm1; sr[2] = sr[1] * gm1; sr[3] = sr[2] * gm1;
            m16p[1] = gm16; m16p[2] = gm16 * gm16; m16p[3] = m16p[2] * gm16;
        }
#pragma unroll
        for (int mi = 0; mi < 8; ++mi)
#pragma unroll
            for (int ni = 0; ni < 4; ++ni)
#pragma unroll
                for (int r = 0; r < 4; ++r) {
                    int m = mbase + mi * 16 + g4 + r;
                    int n = nbase + ni * 16 + q_lane;
                    int s = m & 2047, b = m >> 11, h = n >> 6, d = n & 63, j = d & 31;
                    float v  = acc[mi][ni][r];
                    float v2 = acc[mi][ni ^ 2][r];     // partner d +/- 32 (same lane)
                    float cs = cosT[s * 32 + j], sn = sinT[s * 32 + j];
                    float rot = (d < 32) ? -v2 : v2;
                    float o = v * cs + rot * sn;
                    dst[((size_t)(b * 16 + h) * 2048 + s) * 64 + d] = f2bf(o);
                    if (mode == 1) {
                        // kTs[bh][d][s] = k * gamma_h^{63 - (s&63)};  s&63 keyed by mi&3
                        kTs[((size_t)((b * 16 + h) * 64 + d)) * 2048 + s]
                            = f2bf(o * (sr[r] * m16p[mi & 3]));
                    }
                }
    } else if (mode == 2) {   // acc = C^T: row=n(feature), col=m(token)
#pragma unroll
        for (int mi = 0; mi < 8; ++mi)
#pragma unroll
            for (int ni = 0; ni < 4; ++ni)
#pragma unroll
                for (int r = 0; r < 4; ++r) {
                    int n = nbase + ni * 16 + g4 + r;
                    int m = mbase + mi * 16 + q_lane;
                    int b = m >> 11, s = m & 2047, h = n >> 6, d = n & 63;
                    vT[((size_t)((b * 16 + h) * 64 + d)) * 2048 + s] = f2bf(acc[mi][ni][r]);
                }
    } else {   // mode 3: SiLU gate bf16
#pragma unroll
        for (int mi = 0; mi < 8; ++mi)
#pragma unroll
            for (int ni = 0; ni < 4; ++ni)
#pragma unroll
                for (int r = 0; r < 4; ++r) {
                    int m = mbase + mi * 16 + g4 + r;
                    int n = nbase + ni * 16 + q_lane;
                    float v = acc[mi][ni][r];
                    gate[(size_t)m * 1024 + n] = f2bf(v / (1.0f + expf(-v)));
                }
    }
}

// ---------------------------------------------------------------------------
// Final GEMM: out[4096,1024] = a2 @ Wo^T (f32 out).  128x64 tile, BK=64,
// 4 waves (2x2 of 64x32), r8-proven double-buffer 2-phase, 512 blocks (3/CU).
// ---------------------------------------------------------------------------
__launch_bounds__(256, 3)
__global__ void gemm_out(const unsigned short* __restrict__ A_a2,
                         const unsigned short* __restrict__ Wo,
                         float* __restrict__ outf) {
    __shared__ __align__(16) unsigned short Ash[2][128 * 64];
    __shared__ __align__(16) unsigned short Bsh[2][64 * 64];

    int tid = threadIdx.x;
    int lane = tid & 63, wid = tid >> 6;
    int wm = wid >> 1, wn = wid & 1;
    int m0 = blockIdx.y * 128, n0 = blockIdx.x * 64;

    int l_row = lane >> 3;
    int l_src = ((lane & 7) ^ l_row) << 3;
    const unsigned short* Ab = A_a2 + (size_t)(m0 + wid * 32 + l_row) * 1024 + l_src;
    const unsigned short* Wb = Wo   + (size_t)(n0 + wid * 16 + l_row) * 1024 + l_src;

    f32x4 acc[4][2];
#pragma unroll
    for (int i = 0; i < 4; ++i)
#pragma unroll
        for (int j = 0; j < 2; ++j)
#pragma unroll
            for (int r = 0; r < 4; ++r) acc[i][j][r] = 0.0f;

    auto stage = [&](int buf, int k0) {
#pragma unroll
        for (int i = 0; i < 4; ++i)
            GLL16(Ab + (size_t)(i * 8) * 1024 + k0, &Ash[buf][(wid * 32 + i * 8) * 64]);
#pragma unroll
        for (int i = 0; i < 2; ++i)
            GLL16(Wb + (size_t)(i * 8) * 1024 + k0, &Bsh[buf][(wid * 16 + i * 8) * 64]);
    };

    auto compute = [&](int buf) {
#pragma unroll
        for (int ks = 0; ks < 2; ++ks) {
            bf16x8 af[4], bfv[2];
            int c = ks * 4 + (lane >> 4);
#pragma unroll
            for (int mi = 0; mi < 4; ++mi) {
                int row = wm * 64 + mi * 16 + (lane & 15);
                af[mi] = *(const bf16x8*)&Ash[buf][row * 64 + ((c ^ (row & 7)) << 3)];
            }
#pragma unroll
            for (int ni = 0; ni < 2; ++ni) {
                int row = wn * 32 + ni * 16 + (lane & 15);
                bfv[ni] = *(const bf16x8*)&Bsh[buf][row * 64 + ((c ^ (row & 7)) << 3)];
            }
            __builtin_amdgcn_s_setprio(1);
#pragma unroll
            for (int mi = 0; mi < 4; ++mi)
#pragma unroll
                for (int ni = 0; ni < 2; ++ni)
                    acc[mi][ni] = MFMA_BF16(af[mi], bfv[ni], acc[mi][ni], 0, 0, 0);
            __builtin_amdgcn_s_setprio(0);
        }
    };

    stage(0, 0);
    WAITV(0);
    __syncthreads();
    for (int t = 0; t < 15; ++t) {
        int cur = t & 1;
        stage(cur ^ 1, (t + 1) * 64);
        compute(cur);
        WAITV(0);
        __syncthreads();
    }
    compute(1);

    int mbase = m0 + wm * 64, nbase = n0 + wn * 32;
    int g4 = (lane >> 4) << 2;
#pragma unroll
    for (int mi = 0; mi < 4; ++mi)
#pragma unroll
        for (int ni = 0; ni < 2; ++ni)
#pragma unroll
            for (int r = 0; r < 4; ++r) {
                int m = mbase + mi * 16 + g4 + r;
                int n = nbase + ni * 16 + (lane & 15);
                outf[(size_t)m * 1024 + n] = acc[mi][ni][r];
            }
}

// ---------------------------------------------------------------------------
// Phase A: per-chunk local state  LT[bh][c][d2][d1] = sum_i V[i][d2]*K'[i][d1]
// (K' = gamma^{63-i}-scaled K = kTs).  256 blocks x 256 thr; wave = one chunk.
// ---------------------------------------------------------------------------
__launch_bounds__(256, 4)
__global__ void chunk_state_kernel(const unsigned short* __restrict__ vT,
                                   const unsigned short* __restrict__ kTs,
                                   unsigned short* __restrict__ LT) {
    int tid = threadIdx.x, lane = tid & 63, wid = tid >> 6;
    int bh = blockIdx.x >> 3;
    int c  = (blockIdx.x & 7) * 4 + wid;
    int q_lane = lane & 15;
    int g4 = (lane >> 4) << 2, g8 = (lane >> 4) << 3;

    const unsigned short* vb = vT  + (size_t)bh * 131072 + (size_t)c * 64;
    const unsigned short* kb = kTs + (size_t)bh * 131072 + (size_t)c * 64;

    f32x4 acc[4][4];
#pragma unroll
    for (int i = 0; i < 4; ++i)
#pragma unroll
        for (int j = 0; j < 4; ++j)
#pragma unroll
            for (int r = 0; r < 4; ++r) acc[i][j][r] = 0.0f;

#pragma unroll
    for (int ks = 0; ks < 2; ++ks) {
        bf16x8 a[4], bv[4];
#pragma unroll
        for (int mi = 0; mi < 4; ++mi)
            a[mi] = *(const bf16x8*)(vb + (size_t)(mi * 16 + q_lane) * 2048 + ks * 32 + g8);
#pragma unroll
        for (int ni = 0; ni < 4; ++ni)
            bv[ni] = *(const bf16x8*)(kb + (size_t)(ni * 16 + q_lane) * 2048 + ks * 32 + g8);
#pragma unroll
        for (int mi = 0; mi < 4; ++mi)
#pragma unroll
            for (int ni = 0; ni < 4; ++ni)
                acc[mi][ni] = MFMA_BF16(a[mi], bv[ni], acc[mi][ni], 0, 0, 0);
    }

    unsigned short* lp = LT + ((size_t)(bh * 32 + c)) * 4096;
#pragma unroll
    for (int mi = 0; mi < 4; ++mi)
#pragma unroll
        for (int ni = 0; ni < 4; ++ni)
#pragma unroll
            for (int r = 0; r < 4; ++r) {
                int d2 = mi * 16 + g4 + r;
                int d1 = ni * 16 + q_lane;
                lp[d2 * 64 + d1] = f2bf(acc[mi][ni][r]);
            }
}

// ---------------------------------------------------------------------------
// Phase B: scan over 32 chunks: ST[c] = S_pre (bf16), S = gamma^64*S + LT[c].
// 128 blocks x 256 thr; thread owns 4 consecutive elements of one bh's state.
// ---------------------------------------------------------------------------
__launch_bounds__(256, 4)
__global__ void scan_kernel(const unsigned short* __restrict__ LT,
                            unsigned short* __restrict__ ST) {
    int bh = blockIdx.x >> 2;
    int e0 = ((blockIdx.x & 3) * 256 + threadIdx.x) * 4;
    int h = bh & 15;
    float lg2g = log2f(1.0f - exp2f(-5.0f - (float)h));
    float g64 = exp2f(64.0f * lg2g);

    float s0 = 0.f, s1 = 0.f, s2 = 0.f, s3 = 0.f;
    const unsigned short* lp = LT + (size_t)bh * 32 * 4096 + e0;
    unsigned short* sp = ST + (size_t)bh * 32 * 4096 + e0;
    for (int c = 0; c < 32; ++c) {
        u32x2 wv;
        wv[0] = cvt_pk_bf16(s0, s1);
        wv[1] = cvt_pk_bf16(s2, s3);
        *(u32x2*)sp = wv;                       // pre-state (zeros for c=0)
        bf16x4v lv = *(const bf16x4v*)lp;
        s0 = s0 * g64 + bf2f((unsigned short)lv[0]);
        s1 = s1 * g64 + bf2f((unsigned short)lv[1]);
        s2 = s2 * g64 + bf2f((unsigned short)lv[2]);
        s3 = s3 * g64 + bf2f((unsigned short)lv[3]);
        lp += 4096; sp += 4096;
    }
}

// ---------------------------------------------------------------------------
// Phase C: per (bh, chunk c): O = 0.125*gamma^{i+1} Q@S^T_B + intra, then
// GroupNorm + gate.  1024 blocks x 4 waves x 16 q-rows; no barriers.
// ---------------------------------------------------------------------------
__launch_bounds__(256, 4)
__global__ void retention_chunk_kernel(const unsigned short* __restrict__ qh,
                                       const unsigned short* __restrict__ kh,
                                       const unsigned short* __restrict__ vT,
                                       const unsigned short* __restrict__ ST,
                                       const float* __restrict__ gn_w, const float* __restrict__ gn_b,
                                       const unsigned short* __restrict__ gate,
                                       unsigned short* __restrict__ a2) {
    __shared__ __align__(16) unsigned short Ssh[4][16 * 40];  // per-wave, 80B pitch

    int tid = threadIdx.x, lane = tid & 63, wid = tid >> 6;
    int c = blockIdx.x, bh = blockIdx.y;
    int b = bh >> 4, h = bh & 15;

    float lg2g = log2f(1.0f - exp2f(-5.0f - (float)h));
    float gam1 = exp2f(lg2g);               // gamma
    float gmr1 = exp2f(-lg2g);              // gamma^-1
    float gmr2 = gmr1 * gmr1, gmr3 = gmr2 * gmr1;
    float gmr16 = exp2f(-16.0f * lg2g);

    int q_lane = lane & 15;
    int g4 = (lane >> 4) << 2, g8 = (lane >> 4) << 3;
    int i_col = wid * 16 + q_lane;          // local q index (this lane's column)
    int s_abs = c * 64 + i_col;

    // Q fragments
    bf16x8 aq0, aq1;
    {
        const unsigned short* qp = qh + ((size_t)bh * 2048 + s_abs) * 64 + g8;
        aq0 = *(const bf16x8*)(qp);
        aq1 = *(const bf16x8*)(qp + 32);
    }

    f32x4 z4 = {0.f, 0.f, 0.f, 0.f};
    f32x4 o0, o1, o2, o3;

    // ---- cross-chunk: O = Q @ S^T_asB   (B-frag rows = output d)
    {
        const unsigned short* stp = ST + ((size_t)(bh * 32 + c)) * 4096
                                  + (size_t)q_lane * 64 + g8;
        bf16x8 s00 = *(const bf16x8*)(stp);
        bf16x8 s01 = *(const bf16x8*)(stp + 32);
        bf16x8 s10 = *(const bf16x8*)(stp + 1024);
        bf16x8 s11 = *(const bf16x8*)(stp + 1056);
        bf16x8 s20 = *(const bf16x8*)(stp + 2048);
        bf16x8 s21 = *(const bf16x8*)(stp + 2080);
        bf16x8 s30 = *(const bf16x8*)(stp + 3072);
        bf16x8 s31 = *(const bf16x8*)(stp + 3104);
        o0 = MFMA_BF16(aq0, s00, z4, 0, 0, 0); o0 = MFMA_BF16(aq1, s01, o0, 0, 0, 0);
        o1 = MFMA_BF16(aq0, s10, z4, 0, 0, 0); o1 = MFMA_BF16(aq1, s11, o1, 0, 0, 0);
        o2 = MFMA_BF16(aq0, s20, z4, 0, 0, 0); o2 = MFMA_BF16(aq1, s21, o2, 0, 0, 0);
        o3 = MFMA_BF16(aq0, s30, z4, 0, 0, 0); o3 = MFMA_BF16(aq1, s31, o3, 0, 0, 0);
    }
    // scale by 0.125 * gamma^{i_row+1}; i_row = wid*16 + g4 + r
    {
        float cs0 = 0.125f * exp2f(lg2g * (float)(wid * 16 + g4 + 1));
        float cs1 = cs0 * gam1, cs2 = cs1 * gam1, cs3 = cs2 * gam1;
        o0[0] *= cs0; o0[1] *= cs1; o0[2] *= cs2; o0[3] *= cs3;
        o1[0] *= cs0; o1[1] *= cs1; o1[2] *= cs2; o1[3] *= cs3;
        o2[0] *= cs0; o2[1] *= cs1; o2[2] *= cs2; o2[3] *= cs3;
        o3[0] *= cs0; o3[1] *= cs1; o3[2] *= cs2; o3[3] *= cs3;
    }

    // ---- intra-chunk: swapped QK^T tiles (32 t each); waves 0-1 need only tile 0
    const unsigned short* kbase = kh + ((size_t)bh * 2048 + c * 64) * 64;
    const unsigned short* vbase = vT + (size_t)bh * 131072 + c * 64;
    unsigned short* ssw = &Ssh[wid][0];
    int ntt = (wid >> 1) + 1;
    for (int tt = 0; tt < ntt; ++tt) {
        int tbase = tt * 32;
        const unsigned short* kp = kbase + (size_t)(tbase + q_lane) * 64 + g8;
        bf16x8 k00 = *(const bf16x8*)(kp);
        bf16x8 k01 = *(const bf16x8*)(kp + 32);
        bf16x8 k10 = *(const bf16x8*)(kp + 1024);
        bf16x8 k11 = *(const bf16x8*)(kp + 1056);
        f32x4 sc0 = z4, sc1 = z4;
        sc0 = MFMA_BF16(k00, aq0, sc0, 0, 0, 0);
        sc0 = MFMA_BF16(k01, aq1, sc0, 0, 0, 0);
        sc1 = MFMA_BF16(k10, aq0, sc1, 0, 0, 0);
        sc1 = MFMA_BF16(k11, aq1, sc1, 0, 0, 0);

        // val = sc * 0.125 * gamma^{i_col - j}, masked j<=i_col.  j = tbase+tb*16+g4+r
        int j0 = tbase + g4;
        float e0 = 0.125f * exp2f(lg2g * (float)(i_col - j0));
        float e1 = e0 * gmr1, e2 = e0 * gmr2, e3 = e0 * gmr3;
        float v00 = (i_col >= j0    ) ? sc0[0] * e0 : 0.0f;
        float v01 = (i_col >= j0 + 1) ? sc0[1] * e1 : 0.0f;
        float v02 = (i_col >= j0 + 2) ? sc0[2] * e2 : 0.0f;
        float v03 = (i_col >= j0 + 3) ? sc0[3] * e3 : 0.0f;
        int j1 = j0 + 16;
        float f0 = e0 * gmr16, f1 = e1 * gmr16, f2 = e2 * gmr16, f3 = e3 * gmr16;
        float v10 = (i_col >= j1    ) ? sc1[0] * f0 : 0.0f;
        float v11 = (i_col >= j1 + 1) ? sc1[1] * f1 : 0.0f;
        float v12 = (i_col >= j1 + 2) ? sc1[2] * f2 : 0.0f;
        float v13 = (i_col >= j1 + 3) ? sc1[3] * f3 : 0.0f;

        u32x2 wA, wB;
        wA[0] = cvt_pk_bf16(v00, v01); wA[1] = cvt_pk_bf16(v02, v03);
        wB[0] = cvt_pk_bf16(v10, v11); wB[1] = cvt_pk_bf16(v12, v13);
        *(u32x2*)&ssw[q_lane * 40 + g4] = wA;
        *(u32x2*)&ssw[q_lane * 40 + 16 + g4] = wB;

        bf16x8 sf = *(const bf16x8*)&ssw[q_lane * 40 + g8];
        bf16x8 bv0 = *(const bf16x8*)(vbase + (size_t)(q_lane) * 2048 + tbase + g8);
        bf16x8 bv1 = *(const bf16x8*)(vbase + (size_t)(16 + q_lane) * 2048 + tbase + g8);
        bf16x8 bv2 = *(const bf16x8*)(vbase + (size_t)(32 + q_lane) * 2048 + tbase + g8);
        bf16x8 bv3 = *(const bf16x8*)(vbase + (size_t)(48 + q_lane) * 2048 + tbase + g8);
        o0 = MFMA_BF16(sf, bv0, o0, 0, 0, 0);
        o1 = MFMA_BF16(sf, bv1, o1, 0, 0, 0);
        o2 = MFMA_BF16(sf, bv2, o2, 0, 0, 0);
        o3 = MFMA_BF16(sf, bv3, o3, 0, 0, 0);
    }

    // ---- GroupNorm over Dh=64 per row, *gate, store bf16 [4096][1024]
    float mean[4], rstd[4];
#pragma unroll
    for (int r = 0; r < 4; ++r) {
        float s1 = o0[r] + o1[r] + o2[r] + o3[r];
        float s2 = o0[r]*o0[r] + o1[r]*o1[r] + o2[r]*o2[r] + o3[r]*o3[r];
#pragma unroll
        for (int m = 1; m < 16; m <<= 1) {
            s1 += __shfl_xor(s1, m);
            s2 += __shfl_xor(s2, m);
        }
        float mu = s1 * 0.015625f;
        mean[r] = mu;
        float var = s2 * 0.015625f - mu * mu;
        rstd[r] = rsqrtf(var + 1e-5f);
    }
    int srow = c * 64 + wid * 16;
#define RT_STORE(OV, DB)                                                    \
    {                                                                       \
        int d = DB * 16 + q_lane;                                           \
        float gw = gn_w[h * 64 + d];                                        \
        float gb = gn_b[h * 64 + d];                                        \
        _Pragma("unroll")                                                   \
        for (int r = 0; r < 4; ++r) {                                       \
            int s_out = srow + g4 + r;                                      \
            size_t gi = ((size_t)(b * 2048 + s_out)) * 1024 + h * 64 + d;   \
            float val = (OV[r] - mean[r]) * rstd[r] * gw + gb;              \
            val *= bf2f(gate[gi]);                                          \
            a2[gi] = f2bf(val);                                             \
        }                                                                   \
    }
    RT_STORE(o0, 0); RT_STORE(o1, 1); RT_STORE(o2, 2); RT_STORE(o3, 3);
#undef RT_STORE
}

// ---------------------------------------------------------------------------
extern "C" void kernel_launch(void* const* d_in, const int* in_sizes, int n_in,
                              void* d_out, int out_size, void* d_ws, size_t ws_size,
                              hipStream_t stream) {
    const float* x    = (const float*)d_in[0];
    const float* Wq   = (const float*)d_in[1];
    const float* Wk   = (const float*)d_in[2];
    const float* Wv   = (const float*)d_in[3];
    const float* Wg   = (const float*)d_in[4];
    const float* Wo   = (const float*)d_in[5];
    const float* gn_w = (const float*)d_in[6];
    const float* gn_b = (const float*)d_in[7];

    // workspace (bf16 shorts unless noted); ~70 MB with aliasing:
    //   LT aliases a2 (dead before phase C writes a2)
    //   ST aliases xb (dead after projection GEMM)
    unsigned short* xb   = (unsigned short*)d_ws;          // 4096*1024
    unsigned short* wqb  = xb  + 4194304;                  // 1024*1024 each
    unsigned short* wkb  = wqb + 1048576;
    unsigned short* wvb  = wkb + 1048576;
    unsigned short* wgb  = wvb + 1048576;
    unsigned short* wob  = wgb + 1048576;
    float*          cosT = (float*)(wob + 1048576);        // 2048*32 f32
    float*          sinT = cosT + 65536;
    unsigned short* q_hm = (unsigned short*)(sinT + 65536);// [bh][s][d]
    unsigned short* k_hm = q_hm + 4194304;                 // [bh][s][d]
    unsigned short* vTb  = k_hm + 4194304;                 // [bh][d][t]
    unsigned short* kTs  = vTb + 4194304;                  // [bh][d][t], gamma-scaled
    unsigned short* a2   = kTs + 4194304;                  // [4096][1024]
    unsigned short* gate = a2  + 4194304;                  // [4096][1024] bf16
    unsigned short* LT   = a2;                             // alias: [bh][c][64][64]
    unsigned short* ST   = xb;                             // alias: [bh][c][64][64]

    float* outf = (float*)d_out;

    convert_kernel<<<dim3(2048), dim3(256), 0, stream>>>(
        x, Wq, Wk, Wv, Wg, Wo, xb, cosT, sinT);
    gemm256_proj<<<dim3(4, 16, 4), dim3(512), 0, stream>>>(
        xb, wqb, wkb, wvb, wgb, cosT, sinT,
        q_hm, k_hm, kTs, vTb, gate);
    chunk_state_kernel<<<dim3(256), dim3(256), 0, stream>>>(vTb, kTs, LT);
    scan_kernel<<<dim3(128), dim3(256), 0, stream>>>(LT, ST);
    retention_chunk_kernel<<<dim3(32, 32), dim3(256), 0, stream>>>(
        q_hm, k_hm, vTb, ST, gn_w, gn_b, gate, a2);
    gemm_out<<<dim3(16, 32, 1), dim3(256), 0, stream>>>(a2, wob, outf);
}

// Round 12
// 115.982 us; speedup vs baseline: 1.1771x; 1.1771x over previous
//
#include <hip/hip_runtime.h>
#include <cstdint>
#include <cstddef>

// ---------------------------------------------------------------------------
// RetentionLayer: x->(QKVG proj + RoPE/SiLU) -> causal decay retention ->
// GroupNorm(64)*gate -> @ Wo^T.   B=2 S=2048 D=1024 H=16 Dh=64. Output f32.
// Retention via CHUNKED RECURRENCE (chunk=64).
// Proj GEMM: r8-proven 128x128, BK=64, double-buffered LDS, global_load_lds
// x16 (pre-swizzled source chunk^(row&7)), one vmcnt(0)+barrier per K-tile.
// Final GEMM: 128x64 tile, 512 blocks, 3 blocks/CU.
// ---------------------------------------------------------------------------

typedef __attribute__((ext_vector_type(4))) float  f32x4;
typedef __attribute__((ext_vector_type(8))) short  bf16x8;
typedef __attribute__((ext_vector_type(4))) short  bf16x4v;
typedef __attribute__((ext_vector_type(2))) unsigned int u32x2;

#define MFMA_BF16 __builtin_amdgcn_mfma_f32_16x16x32_bf16

// global_load_lds width=16: per-lane global src, wave-uniform LDS base
#define GLL16(gp, lp) __builtin_amdgcn_global_load_lds( \
    (const __attribute__((address_space(1))) unsigned int*)(const void*)(gp), \
    (__attribute__((address_space(3))) unsigned int*)(void*)(lp), 16, 0, 0)

#define WAITV0 asm volatile("s_waitcnt vmcnt(0)" ::: "memory")

__device__ __forceinline__ unsigned short f2bf(float f) {
    unsigned u = __float_as_uint(f);
    u += 0x7fffu + ((u >> 16) & 1u);   // RNE
    return (unsigned short)(u >> 16);
}
__device__ __forceinline__ float bf2f(unsigned short h) {
    return __uint_as_float(((unsigned)h) << 16);
}
__device__ __forceinline__ unsigned cvt_pk_bf16(float lo, float hi) {
    unsigned r;
    asm("v_cvt_pk_bf16_f32 %0, %1, %2" : "=v"(r) : "v"(lo), "v"(hi));
    return r;
}

// ---------------------------------------------------------------------------
// f32 -> bf16 convert: x (4096x1024) then Wq,Wk,Wv,Wg,Wo (1024x1024 each).
// Blocks < 256 additionally fill the RoPE tables (65536 entries each).
// ---------------------------------------------------------------------------
__global__ void convert_kernel(const float* __restrict__ x,
                               const float* __restrict__ wq, const float* __restrict__ wk,
                               const float* __restrict__ wv, const float* __restrict__ wg,
                               const float* __restrict__ wo,
                               unsigned short* __restrict__ dst,
                               float* __restrict__ cosT, float* __restrict__ sinT) {
    const size_t total = 4194304u + 5u * 1048576u;  // 9437184
    for (size_t i = (size_t)blockIdx.x * blockDim.x + threadIdx.x;
         i * 4 < total; i += (size_t)gridDim.x * blockDim.x) {
        size_t e = i * 4;
        const float* src; size_t off;
        if (e < 4194304u) { src = x; off = e; }
        else {
            size_t r = e - 4194304u;
            int w = (int)(r >> 20); off = r & 1048575u;
            src = (w == 0) ? wq : (w == 1) ? wk : (w == 2) ? wv : (w == 3) ? wg : wo;
        }
        f32x4 v = *(const f32x4*)(src + off);
        unsigned short o0 = f2bf(v[0]), o1 = f2bf(v[1]), o2 = f2bf(v[2]), o3 = f2bf(v[3]);
        unsigned long long pack = (unsigned long long)o0 | ((unsigned long long)o1 << 16)
                                | ((unsigned long long)o2 << 32) | ((unsigned long long)o3 << 48);
        *(unsigned long long*)(dst + e) = pack;
    }
    if (blockIdx.x < 256) {
        int i = blockIdx.x * 256 + threadIdx.x;   // 65536 entries
        int s = i >> 5, j = i & 31;
        float inv = exp2f(-(float)j * (13.287712379549449f / 32.0f)); // log2(10000)
        float ang = (float)s * inv;
        cosT[i] = cosf(ang);
        sinT[i] = sinf(ang);
    }
}

// ---------------------------------------------------------------------------
// Projection GEMM (r8-proven): C[4096,1024] = x @ W^T, 128x128 tile, BK=64,
// 4 waves (2x2 of 64x64).  Double-buffered LDS; stage t+1 before compute t;
// one vmcnt(0)+barrier per K-tile; setprio around MFMA.
// mode 0: ->q_hm (+RoPE)     1: ->k_hm (+RoPE) AND kTs (scaled transpose)
// mode 2: ->vT [bh][d][t] (C^T via swapped mfma)   3: ->gate bf16 (SiLU)
// ---------------------------------------------------------------------------
__launch_bounds__(256, 2)
__global__ void gemm_fused(const unsigned short* __restrict__ A_x,
                           const unsigned short* __restrict__ Wq, const unsigned short* __restrict__ Wk,
                           const unsigned short* __restrict__ Wv, const unsigned short* __restrict__ Wg,
                           const float* __restrict__ cosT, const float* __restrict__ sinT,
                           unsigned short* __restrict__ q_hm, unsigned short* __restrict__ k_hm,
                           unsigned short* __restrict__ kTs, unsigned short* __restrict__ vT,
                           unsigned short* __restrict__ gate) {
    int mode = blockIdx.z;
    const unsigned short* A = A_x;
    const unsigned short* W = (mode == 0) ? Wq : (mode == 1) ? Wk :
                              (mode == 2) ? Wv : Wg;

    __shared__ __align__(16) unsigned short Ash[2][128 * 64];
    __shared__ __align__(16) unsigned short Bsh[2][128 * 64];

    int tid = threadIdx.x;
    int lane = tid & 63, wid = tid >> 6;
    int wm = wid >> 1, wn = wid & 1;
    int m0 = blockIdx.y * 128, n0 = blockIdx.x * 128;

    // staging lane geometry: one GLL16 = 8 rows x 128B stripe; lane (r,c) with
    // r=lane>>3, c=lane&7 writes LDS chunk c of row r; source chunk = c ^ r.
    int l_row = lane >> 3;
    int l_src = ((lane & 7) ^ l_row) << 3;   // source col offset (shorts)
    const unsigned short* Ab = A + (size_t)(m0 + wid * 32 + l_row) * 1024 + l_src;
    const unsigned short* Wb = W + (size_t)(n0 + wid * 32 + l_row) * 1024 + l_src;

    f32x4 acc[4][4];
#pragma unroll
    for (int i = 0; i < 4; ++i)
#pragma unroll
        for (int j = 0; j < 4; ++j)
#pragma unroll
            for (int r = 0; r < 4; ++r) acc[i][j][r] = 0.0f;

#define STAGE(BUF, K0)                                                          \
    _Pragma("unroll")                                                           \
    for (int i_ = 0; i_ < 4; ++i_) {                                            \
        GLL16(Ab + (size_t)(i_ * 8) * 1024 + (K0), &Ash[BUF][(wid * 32 + i_ * 8) * 64]); \
        GLL16(Wb + (size_t)(i_ * 8) * 1024 + (K0), &Bsh[BUF][(wid * 32 + i_ * 8) * 64]); \
    }

#define COMPUTE(BUF)                                                            \
    _Pragma("unroll")                                                           \
    for (int ks = 0; ks < 2; ++ks) {                                            \
        bf16x8 af[4], bfv[4];                                                   \
        _Pragma("unroll")                                                       \
        for (int mi = 0; mi < 4; ++mi) {                                        \
            int row = wm * 64 + mi * 16 + (lane & 15);                          \
            int c = ks * 4 + (lane >> 4);                                       \
            af[mi] = *(const bf16x8*)&Ash[BUF][row * 64 + ((c ^ (row & 7)) << 3)]; \
        }                                                                       \
        _Pragma("unroll")                                                       \
        for (int ni = 0; ni < 4; ++ni) {                                        \
            int row = wn * 64 + ni * 16 + (lane & 15);                          \
            int c = ks * 4 + (lane >> 4);                                       \
            bfv[ni] = *(const bf16x8*)&Bsh[BUF][row * 64 + ((c ^ (row & 7)) << 3)]; \
        }                                                                       \
        __builtin_amdgcn_s_setprio(1);                                          \
        if (mode == 2) {   /* C^T: swap operands */                             \
            _Pragma("unroll")                                                   \
            for (int mi = 0; mi < 4; ++mi)                                      \
                _Pragma("unroll")                                               \
                for (int ni = 0; ni < 4; ++ni)                                  \
                    acc[mi][ni] = MFMA_BF16(bfv[ni], af[mi], acc[mi][ni], 0, 0, 0); \
        } else {                                                                \
            _Pragma("unroll")                                                   \
            for (int mi = 0; mi < 4; ++mi)                                      \
                _Pragma("unroll")                                               \
                for (int ni = 0; ni < 4; ++ni)                                  \
                    acc[mi][ni] = MFMA_BF16(af[mi], bfv[ni], acc[mi][ni], 0, 0, 0); \
        }                                                                       \
        __builtin_amdgcn_s_setprio(0);                                          \
    }

    // prologue: stage tile 0, drain, barrier
    STAGE(0, 0)
    WAITV0;
    __syncthreads();

    // main loop: 16 K-tiles; stage t+1 BEFORE computing t (DMA hides under MFMA)
    for (int t = 0; t < 15; ++t) {
        int cur = t & 1;
        STAGE(cur ^ 1, (t + 1) * 64)
        COMPUTE(cur)
        WAITV0;
        __syncthreads();
    }
    COMPUTE(1)   // tile 15 (15&1 == 1), no further staging

#undef STAGE
#undef COMPUTE

    int mbase = m0 + wm * 64, nbase = n0 + wn * 64;
    int g4 = (lane >> 4) << 2;

    if (mode == 0 || mode == 1) {
        unsigned short* dst = (mode == 0) ? q_hm : k_hm;
        // kTs decay scales (mode 1): h = nbase>>6 is wave-uniform (64-wide tile)
        float sr[4] = {1.f, 1.f, 1.f, 1.f}, m16p[4] = {1.f, 1.f, 1.f, 1.f};
        if (mode == 1) {
            float lg = log2f(1.0f - exp2f(-5.0f - (float)(nbase >> 6)));
            float gm1 = exp2f(-lg), gm16 = exp2f(-16.0f * lg);
            sr[0] = exp2f(lg * (float)(63 - g4));       // gamma^{63-g4}
            sr[1] = sr[0] * gm1; sr[2] = sr[1] * gm1; sr[3] = sr[2] * gm1;
            m16p[1] = gm16; m16p[2] = gm16 * gm16; m16p[3] = m16p[2] * gm16;
        }
#pragma unroll
        for (int mi = 0; mi < 4; ++mi)
#pragma unroll
            for (int ni = 0; ni < 4; ++ni)
#pragma unroll
                for (int r = 0; r < 4; ++r) {
                    int m = mbase + mi * 16 + g4 + r;
                    int n = nbase + ni * 16 + (lane & 15);
                    int s = m & 2047, b = m >> 11, h = n >> 6, d = n & 63, j = d & 31;
                    float v  = acc[mi][ni][r];
                    float v2 = acc[mi][ni ^ 2][r];     // partner d +/- 32 (same lane)
                    float cs = cosT[s * 32 + j], sn = sinT[s * 32 + j];
                    float rot = (d < 32) ? -v2 : v2;
                    float o = v * cs + rot * sn;
                    dst[((size_t)(b * 16 + h) * 2048 + s) * 64 + d] = f2bf(o);
                    if (mode == 1) {
                        // kTs[bh][d][s] = k * gamma_h^{63 - (s&63)}
                        kTs[((size_t)((b * 16 + h) * 64 + d)) * 2048 + s]
                            = f2bf(o * (sr[r] * m16p[mi]));
                    }
                }
    } else if (mode == 2) {   // acc = C^T: row=n(feature), col=m(token)
#pragma unroll
        for (int mi = 0; mi < 4; ++mi)
#pragma unroll
            for (int ni = 0; ni < 4; ++ni)
#pragma unroll
                for (int r = 0; r < 4; ++r) {
                    int n = nbase + ni * 16 + g4 + r;
                    int m = mbase + mi * 16 + (lane & 15);
                    int b = m >> 11, s = m & 2047, h = n >> 6, d = n & 63;
                    vT[((size_t)((b * 16 + h) * 64 + d)) * 2048 + s] = f2bf(acc[mi][ni][r]);
                }
    } else {   // mode 3: SiLU gate bf16
#pragma unroll
        for (int mi = 0; mi < 4; ++mi)
#pragma unroll
            for (int ni = 0; ni < 4; ++ni)
#pragma unroll
                for (int r = 0; r < 4; ++r) {
                    int m = mbase + mi * 16 + g4 + r;
                    int n = nbase + ni * 16 + (lane & 15);
                    float v = acc[mi][ni][r];
                    gate[(size_t)m * 1024 + n] = f2bf(v / (1.0f + expf(-v)));
                }
    }
}

// ---------------------------------------------------------------------------
// Final GEMM: out[4096,1024] = a2 @ Wo^T (f32 out).  128x64 tile, BK=64,
// 4 waves (2x2 of 64x32), double-buffer 2-phase, 512 blocks (3 blocks/CU).
// ---------------------------------------------------------------------------
__launch_bounds__(256, 3)
__global__ void gemm_out(const unsigned short* __restrict__ A_a2,
                         const unsigned short* __restrict__ Wo,
                         float* __restrict__ outf) {
    __shared__ __align__(16) unsigned short Ash[2][128 * 64];
    __shared__ __align__(16) unsigned short Bsh[2][64 * 64];

    int tid = threadIdx.x;
    int lane = tid & 63, wid = tid >> 6;
    int wm = wid >> 1, wn = wid & 1;
    int m0 = blockIdx.y * 128, n0 = blockIdx.x * 64;

    int l_row = lane >> 3;
    int l_src = ((lane & 7) ^ l_row) << 3;
    const unsigned short* Ab = A_a2 + (size_t)(m0 + wid * 32 + l_row) * 1024 + l_src;
    const unsigned short* Wb = Wo   + (size_t)(n0 + wid * 16 + l_row) * 1024 + l_src;

    f32x4 acc[4][2];
#pragma unroll
    for (int i = 0; i < 4; ++i)
#pragma unroll
        for (int j = 0; j < 2; ++j)
#pragma unroll
            for (int r = 0; r < 4; ++r) acc[i][j][r] = 0.0f;

    auto stage = [&](int buf, int k0) {
#pragma unroll
        for (int i = 0; i < 4; ++i)
            GLL16(Ab + (size_t)(i * 8) * 1024 + k0, &Ash[buf][(wid * 32 + i * 8) * 64]);
#pragma unroll
        for (int i = 0; i < 2; ++i)
            GLL16(Wb + (size_t)(i * 8) * 1024 + k0, &Bsh[buf][(wid * 16 + i * 8) * 64]);
    };

    auto compute = [&](int buf) {
#pragma unroll
        for (int ks = 0; ks < 2; ++ks) {
            bf16x8 af[4], bfv[2];
            int c = ks * 4 + (lane >> 4);
#pragma unroll
            for (int mi = 0; mi < 4; ++mi) {
                int row = wm * 64 + mi * 16 + (lane & 15);
                af[mi] = *(const bf16x8*)&Ash[buf][row * 64 + ((c ^ (row & 7)) << 3)];
            }
#pragma unroll
            for (int ni = 0; ni < 2; ++ni) {
                int row = wn * 32 + ni * 16 + (lane & 15);
                bfv[ni] = *(const bf16x8*)&Bsh[buf][row * 64 + ((c ^ (row & 7)) << 3)];
            }
            __builtin_amdgcn_s_setprio(1);
#pragma unroll
            for (int mi = 0; mi < 4; ++mi)
#pragma unroll
                for (int ni = 0; ni < 2; ++ni)
                    acc[mi][ni] = MFMA_BF16(af[mi], bfv[ni], acc[mi][ni], 0, 0, 0);
            __builtin_amdgcn_s_setprio(0);
        }
    };

    stage(0, 0);
    WAITV0;
    __syncthreads();
    for (int t = 0; t < 15; ++t) {
        int cur = t & 1;
        stage(cur ^ 1, (t + 1) * 64);
        compute(cur);
        WAITV0;
        __syncthreads();
    }
    compute(1);

    int mbase = m0 + wm * 64, nbase = n0 + wn * 32;
    int g4 = (lane >> 4) << 2;
#pragma unroll
    for (int mi = 0; mi < 4; ++mi)
#pragma unroll
        for (int ni = 0; ni < 2; ++ni)
#pragma unroll
            for (int r = 0; r < 4; ++r) {
                int m = mbase + mi * 16 + g4 + r;
                int n = nbase + ni * 16 + (lane & 15);
                outf[(size_t)m * 1024 + n] = acc[mi][ni][r];
            }
}

// ---------------------------------------------------------------------------
// Phase A: per-chunk local state  LT[bh][c][d2][d1] = sum_i V[i][d2]*K'[i][d1]
// (K' = gamma^{63-i}-scaled K = kTs).  256 blocks x 256 thr; wave = one chunk.
// ---------------------------------------------------------------------------
__launch_bounds__(256, 4)
__global__ void chunk_state_kernel(const unsigned short* __restrict__ vT,
                                   const unsigned short* __restrict__ kTs,
                                   unsigned short* __restrict__ LT) {
    int tid = threadIdx.x, lane = tid & 63, wid = tid >> 6;
    int bh = blockIdx.x >> 3;
    int c  = (blockIdx.x & 7) * 4 + wid;
    int q_lane = lane & 15;
    int g4 = (lane >> 4) << 2, g8 = (lane >> 4) << 3;

    const unsigned short* vb = vT  + (size_t)bh * 131072 + (size_t)c * 64;
    const unsigned short* kb = kTs + (size_t)bh * 131072 + (size_t)c * 64;

    f32x4 acc[4][4];
#pragma unroll
    for (int i = 0; i < 4; ++i)
#pragma unroll
        for (int j = 0; j < 4; ++j)
#pragma unroll
            for (int r = 0; r < 4; ++r) acc[i][j][r] = 0.0f;

#pragma unroll
    for (int ks = 0; ks < 2; ++ks) {
        bf16x8 a[4], bv[4];
#pragma unroll
        for (int mi = 0; mi < 4; ++mi)
            a[mi] = *(const bf16x8*)(vb + (size_t)(mi * 16 + q_lane) * 2048 + ks * 32 + g8);
#pragma unroll
        for (int ni = 0; ni < 4; ++ni)
            bv[ni] = *(const bf16x8*)(kb + (size_t)(ni * 16 + q_lane) * 2048 + ks * 32 + g8);
#pragma unroll
        for (int mi = 0; mi < 4; ++mi)
#pragma unroll
            for (int ni = 0; ni < 4; ++ni)
                acc[mi][ni] = MFMA_BF16(a[mi], bv[ni], acc[mi][ni], 0, 0, 0);
    }

    unsigned short* lp = LT + ((size_t)(bh * 32 + c)) * 4096;
#pragma unroll
    for (int mi = 0; mi < 4; ++mi)
#pragma unroll
        for (int ni = 0; ni < 4; ++ni)
#pragma unroll
            for (int r = 0; r < 4; ++r) {
                int d2 = mi * 16 + g4 + r;
                int d1 = ni * 16 + q_lane;
                lp[d2 * 64 + d1] = f2bf(acc[mi][ni][r]);
            }
}

// ---------------------------------------------------------------------------
// Phase B: scan over 32 chunks: ST[c] = S_pre (bf16), S = gamma^64*S + LT[c].
// 128 blocks x 256 thr; thread owns 4 consecutive elements of one bh's state.
// ---------------------------------------------------------------------------
__launch_bounds__(256, 4)
__global__ void scan_kernel(const unsigned short* __restrict__ LT,
                            unsigned short* __restrict__ ST) {
    int bh = blockIdx.x >> 2;
    int e0 = ((blockIdx.x & 3) * 256 + threadIdx.x) * 4;
    int h = bh & 15;
    float lg2g = log2f(1.0f - exp2f(-5.0f - (float)h));
    float g64 = exp2f(64.0f * lg2g);

    float s0 = 0.f, s1 = 0.f, s2 = 0.f, s3 = 0.f;
    const unsigned short* lp = LT + (size_t)bh * 32 * 4096 + e0;
    unsigned short* sp = ST + (size_t)bh * 32 * 4096 + e0;
    for (int c = 0; c < 32; ++c) {
        u32x2 wv;
        wv[0] = cvt_pk_bf16(s0, s1);
        wv[1] = cvt_pk_bf16(s2, s3);
        *(u32x2*)sp = wv;                       // pre-state (zeros for c=0)
        bf16x4v lv = *(const bf16x4v*)lp;
        s0 = s0 * g64 + bf2f((unsigned short)lv[0]);
        s1 = s1 * g64 + bf2f((unsigned short)lv[1]);
        s2 = s2 * g64 + bf2f((unsigned short)lv[2]);
        s3 = s3 * g64 + bf2f((unsigned short)lv[3]);
        lp += 4096; sp += 4096;
    }
}

// ---------------------------------------------------------------------------
// Phase C: per (bh, chunk c): O = 0.125*gamma^{i+1} Q@S^T_B + intra, then
// GroupNorm + gate.  1024 blocks x 4 waves x 16 q-rows; no barriers.
// ---------------------------------------------------------------------------
__launch_bounds__(256, 4)
__global__ void retention_chunk_kernel(const unsigned short* __restrict__ qh,
                                       const unsigned short* __restrict__ kh,
                                       const unsigned short* __restrict__ vT,
                                       const unsigned short* __restrict__ ST,
                                       const float* __restrict__ gn_w, const float* __restrict__ gn_b,
                                       const unsigned short* __restrict__ gate,
                                       unsigned short* __restrict__ a2) {
    __shared__ __align__(16) unsigned short Ssh[4][16 * 40];  // per-wave, 80B pitch

    int tid = threadIdx.x, lane = tid & 63, wid = tid >> 6;
    int c = blockIdx.x, bh = blockIdx.y;
    int b = bh >> 4, h = bh & 15;

    float lg2g = log2f(1.0f - exp2f(-5.0f - (float)h));
    float gam1 = exp2f(lg2g);               // gamma
    float gmr1 = exp2f(-lg2g);              // gamma^-1
    float gmr2 = gmr1 * gmr1, gmr3 = gmr2 * gmr1;
    float gmr16 = exp2f(-16.0f * lg2g);

    int q_lane = lane & 15;
    int g4 = (lane >> 4) << 2, g8 = (lane >> 4) << 3;
    int i_col = wid * 16 + q_lane;          // local q index (this lane's column)
    int s_abs = c * 64 + i_col;

    // Q fragments
    bf16x8 aq0, aq1;
    {
        const unsigned short* qp = qh + ((size_t)bh * 2048 + s_abs) * 64 + g8;
        aq0 = *(const bf16x8*)(qp);
        aq1 = *(const bf16x8*)(qp + 32);
    }

    f32x4 z4 = {0.f, 0.f, 0.f, 0.f};
    f32x4 o0, o1, o2, o3;

    // ---- cross-chunk: O = Q @ S^T_asB   (B-frag rows = output d)
    {
        const unsigned short* stp = ST + ((size_t)(bh * 32 + c)) * 4096
                                  + (size_t)q_lane * 64 + g8;
        bf16x8 s00 = *(const bf16x8*)(stp);
        bf16x8 s01 = *(const bf16x8*)(stp + 32);
        bf16x8 s10 = *(const bf16x8*)(stp + 1024);
        bf16x8 s11 = *(const bf16x8*)(stp + 1056);
        bf16x8 s20 = *(const bf16x8*)(stp + 2048);
        bf16x8 s21 = *(const bf16x8*)(stp + 2080);
        bf16x8 s30 = *(const bf16x8*)(stp + 3072);
        bf16x8 s31 = *(const bf16x8*)(stp + 3104);
        o0 = MFMA_BF16(aq0, s00, z4, 0, 0, 0); o0 = MFMA_BF16(aq1, s01, o0, 0, 0, 0);
        o1 = MFMA_BF16(aq0, s10, z4, 0, 0, 0); o1 = MFMA_BF16(aq1, s11, o1, 0, 0, 0);
        o2 = MFMA_BF16(aq0, s20, z4, 0, 0, 0); o2 = MFMA_BF16(aq1, s21, o2, 0, 0, 0);
        o3 = MFMA_BF16(aq0, s30, z4, 0, 0, 0); o3 = MFMA_BF16(aq1, s31, o3, 0, 0, 0);
    }
    // scale by 0.125 * gamma^{i_row+1}; i_row = wid*16 + g4 + r
    {
        float cs0 = 0.125f * exp2f(lg2g * (float)(wid * 16 + g4 + 1));
        float cs1 = cs0 * gam1, cs2 = cs1 * gam1, cs3 = cs2 * gam1;
        o0[0] *= cs0; o0[1] *= cs1; o0[2] *= cs2; o0[3] *= cs3;
        o1[0] *= cs0; o1[1] *= cs1; o1[2] *= cs2; o1[3] *= cs3;
        o2[0] *= cs0; o2[1] *= cs1; o2[2] *= cs2; o2[3] *= cs3;
        o3[0] *= cs0; o3[1] *= cs1; o3[2] *= cs2; o3[3] *= cs3;
    }

    // ---- intra-chunk: swapped QK^T tiles (32 t each); waves 0-1 need only tile 0
    const unsigned short* kbase = kh + ((size_t)bh * 2048 + c * 64) * 64;
    const unsigned short* vbase = vT + (size_t)bh * 131072 + c * 64;
    unsigned short* ssw = &Ssh[wid][0];
    int ntt = (wid >> 1) + 1;
    for (int tt = 0; tt < ntt; ++tt) {
        int tbase = tt * 32;
        const unsigned short* kp = kbase + (size_t)(tbase + q_lane) * 64 + g8;
        bf16x8 k00 = *(const bf16x8*)(kp);
        bf16x8 k01 = *(const bf16x8*)(kp + 32);
        bf16x8 k10 = *(const bf16x8*)(kp + 1024);
        bf16x8 k11 = *(const bf16x8*)(kp + 1056);
        f32x4 sc0 = z4, sc1 = z4;
        sc0 = MFMA_BF16(k00, aq0, sc0, 0, 0, 0);
        sc0 = MFMA_BF16(k01, aq1, sc0, 0, 0, 0);
        sc1 = MFMA_BF16(k10, aq0, sc1, 0, 0, 0);
        sc1 = MFMA_BF16(k11, aq1, sc1, 0, 0, 0);

        // val = sc * 0.125 * gamma^{i_col - j}, masked j<=i_col.  j = tbase+tb*16+g4+r
        int j0 = tbase + g4;
        float e0 = 0.125f * exp2f(lg2g * (float)(i_col - j0));
        float e1 = e0 * gmr1, e2 = e0 * gmr2, e3 = e0 * gmr3;
        float v00 = (i_col >= j0    ) ? sc0[0] * e0 : 0.0f;
        float v01 = (i_col >= j0 + 1) ? sc0[1] * e1 : 0.0f;
        float v02 = (i_col >= j0 + 2) ? sc0[2] * e2 : 0.0f;
        float v03 = (i_col >= j0 + 3) ? sc0[3] * e3 : 0.0f;
        int j1 = j0 + 16;
        float f0 = e0 * gmr16, f1 = e1 * gmr16, f2 = e2 * gmr16, f3 = e3 * gmr16;
        float v10 = (i_col >= j1    ) ? sc1[0] * f0 : 0.0f;
        float v11 = (i_col >= j1 + 1) ? sc1[1] * f1 : 0.0f;
        float v12 = (i_col >= j1 + 2) ? sc1[2] * f2 : 0.0f;
        float v13 = (i_col >= j1 + 3) ? sc1[3] * f3 : 0.0f;

        u32x2 wA, wB;
        wA[0] = cvt_pk_bf16(v00, v01); wA[1] = cvt_pk_bf16(v02, v03);
        wB[0] = cvt_pk_bf16(v10, v11); wB[1] = cvt_pk_bf16(v12, v13);
        *(u32x2*)&ssw[q_lane * 40 + g4] = wA;
        *(u32x2*)&ssw[q_lane * 40 + 16 + g4] = wB;

        bf16x8 sf = *(const bf16x8*)&ssw[q_lane * 40 + g8];
        bf16x8 bv0 = *(const bf16x8*)(vbase + (size_t)(q_lane) * 2048 + tbase + g8);
        bf16x8 bv1 = *(const bf16x8*)(vbase + (size_t)(16 + q_lane) * 2048 + tbase + g8);
        bf16x8 bv2 = *(const bf16x8*)(vbase + (size_t)(32 + q_lane) * 2048 + tbase + g8);
        bf16x8 bv3 = *(const bf16x8*)(vbase + (size_t)(48 + q_lane) * 2048 + tbase + g8);
        o0 = MFMA_BF16(sf, bv0, o0, 0, 0, 0);
        o1 = MFMA_BF16(sf, bv1, o1, 0, 0, 0);
        o2 = MFMA_BF16(sf, bv2, o2, 0, 0, 0);
        o3 = MFMA_BF16(sf, bv3, o3, 0, 0, 0);
    }

    // ---- GroupNorm over Dh=64 per row, *gate, store bf16 [4096][1024]
    float mean[4], rstd[4];
#pragma unroll
    for (int r = 0; r < 4; ++r) {
        float s1 = o0[r] + o1[r] + o2[r] + o3[r];
        float s2 = o0[r]*o0[r] + o1[r]*o1[r] + o2[r]*o2[r] + o3[r]*o3[r];
#pragma unroll
        for (int m = 1; m < 16; m <<= 1) {
            s1 += __shfl_xor(s1, m);
            s2 += __shfl_xor(s2, m);
        }
        float mu = s1 * 0.015625f;
        mean[r] = mu;
        float var = s2 * 0.015625f - mu * mu;
        rstd[r] = rsqrtf(var + 1e-5f);
    }
    int srow = c * 64 + wid * 16;
#define RT_STORE(OV, DB)                                                    \
    {                                                                       \
        int d = DB * 16 + q_lane;                                           \
        float gw = gn_w[h * 64 + d];                                        \
        float gb = gn_b[h * 64 + d];                                        \
        _Pragma("unroll")                                                   \
        for (int r = 0; r < 4; ++r) {                                       \
            int s_out = srow + g4 + r;                                      \
            size_t gi = ((size_t)(b * 2048 + s_out)) * 1024 + h * 64 + d;   \
            float val = (OV[r] - mean[r]) * rstd[r] * gw + gb;              \
            val *= bf2f(gate[gi]);                                          \
            a2[gi] = f2bf(val);                                             \
        }                                                                   \
    }
    RT_STORE(o0, 0); RT_STORE(o1, 1); RT_STORE(o2, 2); RT_STORE(o3, 3);
#undef RT_STORE
}

// ---------------------------------------------------------------------------
extern "C" void kernel_launch(void* const* d_in, const int* in_sizes, int n_in,
                              void* d_out, int out_size, void* d_ws, size_t ws_size,
                              hipStream_t stream) {
    const float* x    = (const float*)d_in[0];
    const float* Wq   = (const float*)d_in[1];
    const float* Wk   = (const float*)d_in[2];
    const float* Wv   = (const float*)d_in[3];
    const float* Wg   = (const float*)d_in[4];
    const float* Wo   = (const float*)d_in[5];
    const float* gn_w = (const float*)d_in[6];
    const float* gn_b = (const float*)d_in[7];

    // workspace (bf16 shorts unless noted); ~70 MB with aliasing:
    //   LT aliases a2 (dead before phase C writes a2)
    //   ST aliases xb (dead after projection GEMM)
    unsigned short* xb   = (unsigned short*)d_ws;          // 4096*1024
    unsigned short* wqb  = xb  + 4194304;                  // 1024*1024 each
    unsigned short* wkb  = wqb + 1048576;
    unsigned short* wvb  = wkb + 1048576;
    unsigned short* wgb  = wvb + 1048576;
    unsigned short* wob  = wgb + 1048576;
    float*          cosT = (float*)(wob + 1048576);        // 2048*32 f32
    float*          sinT = cosT + 65536;
    unsigned short* q_hm = (unsigned short*)(sinT + 65536);// [bh][s][d]
    unsigned short* k_hm = q_hm + 4194304;                 // [bh][s][d]
    unsigned short* vTb  = k_hm + 4194304;                 // [bh][d][t]
    unsigned short* kTs  = vTb + 4194304;                  // [bh][d][t], gamma-scaled
    unsigned short* a2   = kTs + 4194304;                  // [4096][1024]
    unsigned short* gate = a2  + 4194304;                  // [4096][1024] bf16
    unsigned short* LT   = a2;                             // alias: [bh][c][64][64]
    unsigned short* ST   = xb;                             // alias: [bh][c][64][64]

    float* outf = (float*)d_out;

    convert_kernel<<<dim3(2048), dim3(256), 0, stream>>>(
        x, Wq, Wk, Wv, Wg, Wo, xb, cosT, sinT);
    gemm_fused<<<dim3(8, 32, 4), dim3(256), 0, stream>>>(
        xb, wqb, wkb, wvb, wgb, cosT, sinT,
        q_hm, k_hm, kTs, vTb, gate);
    chunk_state_kernel<<<dim3(256), dim3(256), 0, stream>>>(vTb, kTs, LT);
    scan_kernel<<<dim3(128), dim3(256), 0, stream>>>(LT, ST);
    retention_chunk_kernel<<<dim3(32, 32), dim3(256), 0, stream>>>(
        q_hm, k_hm, vTb, ST, gn_w, gn_b, gate, a2);
    gemm_out<<<dim3(16, 32, 1), dim3(256), 0, stream>>>(a2, wob, outf);
}